// Round 23
// baseline (352.644 us; speedup 1.0000x reference)
//
#include <hip/hip_runtime.h>
#include <hip/hip_bf16.h>

typedef __attribute__((ext_vector_type(8))) short bf16x8;
typedef __attribute__((ext_vector_type(4))) float f32x4;
typedef __attribute__((ext_vector_type(16))) float f32x16;

#define DHEAD 64
#define L_SEQ 2048
#define QSCALE (0.125f * 1.44269504088896340736f)

// ws: [4KB, +2MB) ml float2[(bh*8+T)*4+s][256]
//     [4KB+2MB, +22MB) partial O bf16, compact slots [32*22][256][64]
//     slot(bh,T,s>=1) = bh*22 + (T==0 ? 0 : 1+(T-1)*3+(s-1))
#define WS_ML_OFF   4096
#define WS_PART_OFF (4096 + 32 * 8 * 4 * 256 * 8)
#define WS_NEED     ((size_t)WS_PART_OFF + (size_t)32 * 22 * 256 * 64 * 2)

union U4S8 { uint4 u; bf16x8 s; };

__device__ __forceinline__ unsigned pk2(float a, float b) {
    unsigned r;
    asm("v_cvt_pk_bf16_f32 %0, %1, %2" : "=v"(r) : "v"(a), "v"(b));
    return r;
}
__device__ __forceinline__ float bfrt(float x) {
    return __uint_as_float(pk2(x, x) << 16);
}
__device__ __forceinline__ float bf2f(unsigned short u) {
    return __uint_as_float((unsigned)u << 16);
}
__device__ __forceinline__ float fexp2(float x) {
#if __has_builtin(__builtin_amdgcn_exp2f)
    return __builtin_amdgcn_exp2f(x);
#else
    return __expf(x * 0.69314718055994530942f);
#endif
}

#if __has_builtin(__builtin_amdgcn_permlane32_swap)
__device__ __forceinline__ float xhalf_max(float x) {
    const unsigned u = __float_as_uint(x);
    const auto r = __builtin_amdgcn_permlane32_swap(u, u, false, false);
    return fmaxf(__uint_as_float(r[0]), __uint_as_float(r[1]));
}
__device__ __forceinline__ float xhalf_sum(float x) {
    const unsigned u = __float_as_uint(x);
    const auto r = __builtin_amdgcn_permlane32_swap(u, u, false, false);
    return __uint_as_float(r[0]) + __uint_as_float(r[1]);
}
#else
__device__ __forceinline__ float xhalf_max(float x) { return fmaxf(x, __shfl_xor(x, 32)); }
__device__ __forceinline__ float xhalf_sum(float x) { return x + __shfl_xor(x, 32); }
#endif

#define MAX16(P) fmaxf(fmaxf(fmaxf(fmaxf(P[0],P[1]),fmaxf(P[2],P[3])),          \
                             fmaxf(fmaxf(P[4],P[5]),fmaxf(P[6],P[7]))),         \
                       fmaxf(fmaxf(fmaxf(P[8],P[9]),fmaxf(P[10],P[11])),        \
                             fmaxf(fmaxf(P[12],P[13]),fmaxf(P[14],P[15]))))
#define SUM16(P) ((((P[0]+P[1])+(P[2]+P[3]))+((P[4]+P[5])+(P[6]+P[7])))         \
                + (((P[8]+P[9])+(P[10]+P[11]))+((P[12]+P[13])+(P[14]+P[15]))))

// QBLK=256: wave owns 64 q-rows (2 MFMA groups) -> per staged 128-key tile
// 32 MFMA/wave with UNCHANGED staging bytes (r21 proved bytes/tile is the
// residual). 1024 jobs = 32bh x 8T x 4 kv-stride-segs, LPT; ~2-3 blocks/CU
// resident + backfill. Merge = 4-way (r14-proven scheme).
// Entry = (T<<2)|s; job tiles kt = s, s+4, ... <= 2T+1.
__constant__ unsigned char JOBS32[32] = {
    (7<<2)|0, (7<<2)|1, (7<<2)|2, (7<<2)|3, (6<<2)|0, (6<<2)|1,            // d=4
    (6<<2)|2, (6<<2)|3, (5<<2)|0, (5<<2)|1, (5<<2)|2, (5<<2)|3,
    (4<<2)|0, (4<<2)|1,                                                    // d=3
    (4<<2)|2, (4<<2)|3, (3<<2)|0, (3<<2)|1, (3<<2)|2, (3<<2)|3,
    (2<<2)|0, (2<<2)|1,                                                    // d=2
    (2<<2)|2, (2<<2)|3, (1<<2)|0, (1<<2)|1, (1<<2)|2, (1<<2)|3,
    (0<<2)|0, (0<<2)|1,                                                    // d=1
    (0<<2)|2, (0<<2)|3,                                                    // d=0
};

// LDS map (proven r13-r22): K chunk kb*4+kc, slot l: K[kb*32+(l&31)][kc*16+8*(l>>5)+j]
//                           V chunk kv*2+dt, slot l: V[kv*16+8*(l>>5)+j][dt*32+(l&31)]
template<int MODE>   // 1 = split4 + merge; 0 = basic (no ws)
__global__ __launch_bounds__(256, 2)
void fattn_kernel(const float* __restrict__ Qg, const float* __restrict__ Kg,
                  const float* __restrict__ Vg, float* __restrict__ Og,
                  char* __restrict__ wsBase) {
    __shared__ uint4 sK4[16][64];
    __shared__ uint4 sV4[16][65];

    const int tid  = threadIdx.x;
    const int lane = tid & 63;
    const int w    = tid >> 6;
    const int hi   = lane >> 5;
    const int c    = lane & 31;

    const int id  = blockIdx.x;
    const int bh  = (id & 7) + 8 * ((id >> 3) & 3);   // 4 bh per XCD

    int T, s, kt0, kstep, d;
    if (MODE == 1) {
        const unsigned jb = JOBS32[id >> 5];          // LPT rank
        T = jb >> 2; s = jb & 3;
        d = (s <= 2 * T + 1) ? (((2 * T + 1 - s) >> 2) + 1) : 0;
        if (d == 0) return;
        kt0 = s; kstep = 4;
    } else {
        const int u_ = id >> 5;                       // grid 256: u 0..7
        T = (u_ < 4) ? (7 - u_) : (u_ - 4);
        s = 0; kt0 = 0; kstep = 1; d = 2 * T + 2;
    }

    const size_t base = (size_t)bh * L_SEQ * DHEAD;
    const int q0w = T * 256 + w * 64;    // this wave's 64 q-rows (2 groups of 32)

    // ---- Q fragments for both groups (B-operand), scale folded ----
    bf16x8 qf[2][4];
    #pragma unroll
    for (int g = 0; g < 2; ++g) {
        const float* Qrow = Qg + base + (size_t)(q0w + 32 * g + c) * DHEAD;
        #pragma unroll
        for (int kc = 0; kc < 4; ++kc) {
            float4 aa = *(const float4*)(Qrow + kc * 16 + hi * 8);
            float4 bb = *(const float4*)(Qrow + kc * 16 + hi * 8 + 4);
            U4S8 t;
            t.u = make_uint4(pk2(aa.x * QSCALE, aa.y * QSCALE),
                             pk2(aa.z * QSCALE, aa.w * QSCALE),
                             pk2(bb.x * QSCALE, bb.y * QSCALE),
                             pk2(bb.z * QSCALE, bb.w * QSCALE));
            qf[g][kc] = t.s;
        }
    }

    // ---- staging (r22-proven mappings) ----
    const float* Kpb = Kg + base + (size_t)(32 * w + c) * DHEAD + 32 * hi;
    const int kg = tid >> 4, dq = tid & 15;
    const float* VpB = Vg + base + (size_t)(kg * 8) * DHEAD + dq * 4;

    auto stage_K = [&](int kt) {
        float4 rk[8];
        const float* Kp = Kpb + (size_t)kt * 128 * DHEAD;
        #pragma unroll
        for (int t = 0; t < 8; ++t) rk[t] = *(const float4*)(Kp + 4 * t);
        #pragma unroll
        for (int q = 0; q < 2; ++q)
            #pragma unroll
            for (int hh = 0; hh < 2; ++hh) {
                const float4 r0 = rk[4 * q + 2 * hh], r1 = rk[4 * q + 2 * hh + 1];
                sK4[w * 4 + 2 * hi + q][hh * 32 + c] =
                    make_uint4(pk2(r0.x, r0.y), pk2(r0.z, r0.w),
                               pk2(r1.x, r1.y), pk2(r1.z, r1.w));
            }
    };
    auto stage_V = [&](int kt) {
        f32x4 rv4[8];
        const float* Vp = VpB + (size_t)kt * 128 * DHEAD;
        #pragma unroll
        for (int j = 0; j < 8; ++j) rv4[j] = *(const f32x4*)(Vp + j * DHEAD);
        #pragma unroll
        for (int dd = 0; dd < 4; ++dd) {
            const int dv = dq * 4 + dd;
            const int ch = (kg >> 1) * 2 + (dv >> 5);
            const int sl = ((kg & 1) << 5) | (dv & 31);
            sV4[ch][sl] = make_uint4(pk2(rv4[0][dd], rv4[1][dd]),
                                     pk2(rv4[2][dd], rv4[3][dd]),
                                     pk2(rv4[4][dd], rv4[5][dd]),
                                     pk2(rv4[6][dd], rv4[7][dd]));
        }
    };

    f32x16 o0[2], o1[2];
    #pragma unroll
    for (int g = 0; g < 2; ++g) {
        o0[g] = (f32x16){0,0,0,0,0,0,0,0,0,0,0,0,0,0,0,0};
        o1[g] = o0[g];
    }
    float m_r[2] = {-1e30f, -1e30f}, l_r[2] = {0.f, 0.f};

    stage_K(kt0);
    stage_V(kt0);
    __syncthreads();

    for (int j = 0; j < d; ++j) {
        const int  kt = kt0 + j * kstep;
        const bool pf = (j + 1 < d);

        #pragma unroll
        for (int sub = 0; sub < 2; ++sub) {
            #pragma unroll
            for (int g = 0; g < 2; ++g) {
                // causal: 32-key block 4kt+2sub+i live iff <= 8T+2w+g
                const int lim = 8 * T + 2 * w + g - (4 * kt + 2 * sub) + 1;
                const int nkb = lim < 0 ? 0 : (lim > 2 ? 2 : lim);
                if (nkb > 0) {
                    float p[2][16];

                    __builtin_amdgcn_s_setprio(1);
                    #pragma unroll
                    for (int i = 0; i < 2; ++i) {
                        if (i < nkb) {
                            f32x16 sa = {0,0,0,0,0,0,0,0,0,0,0,0,0,0,0,0};
                            #pragma unroll
                            for (int kc = 0; kc < 4; ++kc) {
                                U4S8 t; t.u = sK4[(2 * sub + i) * 4 + kc][lane];
                                sa = __builtin_amdgcn_mfma_f32_32x32x16_bf16(t.s, qf[g][kc], sa, 0, 0, 0);
                            }
                            #pragma unroll
                            for (int r = 0; r < 16; ++r) p[i][r] = sa[r];
                        }
                    }
                    __builtin_amdgcn_s_setprio(0);

                    // diagonal 32x32 mask (compile-time i, runtime condition)
                    #pragma unroll
                    for (int i = 0; i < 2; ++i) {
                        if (4 * kt + 2 * sub + i == 8 * T + 2 * w + g) {
                            #pragma unroll
                            for (int r = 0; r < 16; ++r) {
                                const int kk = (r & 3) + 8 * (r >> 2) + 4 * hi;
                                if (kk > c) p[i][r] = -1e30f;
                            }
                        }
                    }

                    float mx = MAX16(p[0]);
                    if (nkb > 1) mx = fmaxf(mx, MAX16(p[1]));
                    mx = xhalf_max(mx);

                    if (__any(mx > m_r[g] + 8.f)) {      // defer-max
                        const float mn    = fmaxf(m_r[g], mx);
                        const float alpha = fexp2(m_r[g] - mn);
                        m_r[g]  = mn;
                        l_r[g] *= alpha;
                        #pragma unroll
                        for (int r = 0; r < 16; ++r) {
                            const float ab = __shfl(alpha, (r & 3) + 8 * (r >> 2) + 4 * hi);
                            o0[g][r] *= ab; o1[g][r] *= ab;
                        }
                    }

                    #pragma unroll
                    for (int i = 0; i < 2; ++i) {
                        if (i < nkb) {
                            #pragma unroll
                            for (int r = 0; r < 16; ++r) p[i][r] = fexp2(p[i][r] - m_r[g]);
                        }
                    }
                    float rs = SUM16(p[0]);
                    if (nkb > 1) rs += SUM16(p[1]);
                    rs = xhalf_sum(rs);
                    l_r[g] += rs;

                    __builtin_amdgcn_s_setprio(1);
                    #pragma unroll
                    for (int kcl = 0; kcl < 4; ++kcl) {
                        if (kcl < 2 * nkb) {
                            const int i = kcl >> 1, bs = (kcl & 1) * 8;
                            unsigned a0 = pk2(p[i][bs + 0], p[i][bs + 1]);
                            unsigned a1 = pk2(p[i][bs + 2], p[i][bs + 3]);
                            unsigned b0 = pk2(p[i][bs + 4], p[i][bs + 5]);
                            unsigned b1 = pk2(p[i][bs + 6], p[i][bs + 7]);
                            asm("v_permlane32_swap_b32 %0, %1" : "+v"(a0), "+v"(b0));
                            asm("v_permlane32_swap_b32 %0, %1" : "+v"(a1), "+v"(b1));
                            U4S8 t;
                            t.u = make_uint4(a0, a1, b0, b1);
                            const int kv = 4 * sub + kcl;
                            U4S8 tv0; tv0.u = sV4[kv * 2][lane];
                            o0[g] = __builtin_amdgcn_mfma_f32_32x32x16_bf16(t.s, tv0.s, o0[g], 0, 0, 0);
                            U4S8 tv1; tv1.u = sV4[kv * 2 + 1][lane];
                            o1[g] = __builtin_amdgcn_mfma_f32_32x32x16_bf16(t.s, tv1.s, o1[g], 0, 0, 0);
                        }
                    }
                    __builtin_amdgcn_s_setprio(0);
                }
            }
        }

        if (pf) {
            __syncthreads();
            stage_K(kt + kstep);
            stage_V(kt + kstep);
            __syncthreads();
        }
    }

    float* Op = Og + base;

    if (MODE == 0) {
        #pragma unroll
        for (int g = 0; g < 2; ++g) {
            const float linv = 1.f / l_r[g];
            #pragma unroll
            for (int r = 0; r < 16; ++r) {
                const int   cr  = (r & 3) + 8 * (r >> 2) + 4 * hi;
                const float lb  = __shfl(linv, cr);
                const int   row = q0w + 32 * g + cr;
                Op[(size_t)row * DHEAD + c]      = o0[g][r] * lb;
                Op[(size_t)row * DHEAD + 32 + c] = o1[g][r] * lb;
            }
        }
        return;
    }

    // ---- publish partial, write-only; merge_kernel combines ----
    float2* ml = (float2*)(wsBase + WS_ML_OFF);
    const size_t mlb = (size_t)((bh * 8 + T) * 4 + s) * 256;
    #pragma unroll
    for (int g = 0; g < 2; ++g)
        if (hi == 0) ml[mlb + w * 64 + 32 * g + c] = make_float2(m_r[g], l_r[g]);
    if (s == 0) {           // seg0 partial (bf16-rounded, unnormalized) in d_out
        #pragma unroll
        for (int g = 0; g < 2; ++g)
            #pragma unroll
            for (int r = 0; r < 16; ++r) {
                const int cr  = (r & 3) + 8 * (r >> 2) + 4 * hi;
                const int row = q0w + 32 * g + cr;
                Op[(size_t)row * DHEAD + c]      = bfrt(o0[g][r]);
                Op[(size_t)row * DHEAD + 32 + c] = bfrt(o1[g][r]);
            }
    } else {                // seg>=1 partial as bf16 in compact ws slot
        const int ps = bh * 22 + (T == 0 ? 0 : 1 + (T - 1) * 3 + (s - 1));
        unsigned short* mp = (unsigned short*)(wsBase + WS_PART_OFF) + (size_t)ps * 256 * 64;
        #pragma unroll
        for (int g = 0; g < 2; ++g)
            #pragma unroll
            for (int r = 0; r < 16; ++r) {
                const int cr   = (r & 3) + 8 * (r >> 2) + 4 * hi;
                const int lrow = w * 64 + 32 * g + cr;
                mp[lrow * 64 + c]      = (unsigned short)pk2(o0[g][r], o0[g][r]);
                mp[lrow * 64 + 32 + c] = (unsigned short)pk2(o1[g][r], o1[g][r]);
            }
    }
}

// n-way merge: one block per (bh,T); n = min(4, 2T+2).
__global__ __launch_bounds__(256)
void merge_kernel(float* __restrict__ Og, const char* __restrict__ wsBase) {
    const int blk = blockIdx.x;           // 256 = 32 bh x 8 T
    const int bh = blk >> 3, T = blk & 7;
    const int n  = (T == 0) ? 2 : 4;
    const size_t f4 = (size_t)((bh * 8 + T) * 4);
    const int psb = bh * 22 + (T == 0 ? 0 : 1 + (T - 1) * 3);

    const float2* ml = (const float2*)(wsBase + WS_ML_OFF);
    const unsigned short* part = (const unsigned short*)(wsBase + WS_PART_OFF);
    const unsigned short* p1 = part + (size_t)(psb + 0) * 256 * 64;
    const unsigned short* p2 = part + (size_t)(psb + 1) * 256 * 64;
    const unsigned short* p3 = part + (size_t)(psb + 2) * 256 * 64;
    float* Op = Og + ((size_t)bh * L_SEQ + (size_t)T * 256) * DHEAD;

    __shared__ float sA0[256], sA1[256], sA2[256], sA3[256], sLi[256];
    const int t = threadIdx.x;
    {
        const float2 m0 = ml[(f4 + 0) * 256 + t];
        const float2 m1 = ml[(f4 + 1) * 256 + t];
        const float2 m2 = (n > 2) ? ml[(f4 + 2) * 256 + t] : make_float2(-1e30f, 0.f);
        const float2 m3 = (n > 3) ? ml[(f4 + 3) * 256 + t] : make_float2(-1e30f, 0.f);
        const float mM = fmaxf(fmaxf(m0.x, m1.x), fmaxf(m2.x, m3.x));
        const float a0 = fexp2(m0.x - mM), a1 = fexp2(m1.x - mM);
        const float a2 = fexp2(m2.x - mM), a3 = fexp2(m3.x - mM);
        sA0[t] = a0; sA1[t] = a1; sA2[t] = a2; sA3[t] = a3;
        sLi[t] = 1.f / (a0 * m0.y + a1 * m1.y + a2 * m2.y + a3 * m3.y);
    }
    __syncthreads();

    #pragma unroll
    for (int e = 0; e < 16; ++e) {
        const int idx4 = e * 256 + t;     // 4096 float4 groups (256 rows x 16)
        const int row  = idx4 >> 4;
        const int c4   = (idx4 & 15) * 4;
        const int off  = row * 64 + c4;
        const float a0 = sA0[row], li = sLi[row];
        float4 po = *(float4*)&Op[off];
        po.x *= a0; po.y *= a0; po.z *= a0; po.w *= a0;
        {
            const float a1 = sA1[row];
            const ushort4 u = *(const ushort4*)&p1[off];
            po.x += a1 * bf2f(u.x); po.y += a1 * bf2f(u.y);
            po.z += a1 * bf2f(u.z); po.w += a1 * bf2f(u.w);
        }
        if (n > 2) {
            const float a2 = sA2[row];
            const ushort4 u = *(const ushort4*)&p2[off];
            po.x += a2 * bf2f(u.x); po.y += a2 * bf2f(u.y);
            po.z += a2 * bf2f(u.z); po.w += a2 * bf2f(u.w);
        }
        if (n > 3) {
            const float a3 = sA3[row];
            const ushort4 u = *(const ushort4*)&p3[off];
            po.x += a3 * bf2f(u.x); po.y += a3 * bf2f(u.y);
            po.z += a3 * bf2f(u.z); po.w += a3 * bf2f(u.w);
        }
        po.x *= li; po.y *= li; po.z *= li; po.w *= li;
        *(float4*)&Op[off] = po;
    }
}

extern "C" void kernel_launch(void* const* d_in, const int* in_sizes, int n_in,
                              void* d_out, int out_size, void* d_ws, size_t ws_size,
                              hipStream_t stream) {
    const float* Q = (const float*)d_in[0];
    const float* K = (const float*)d_in[1];
    const float* V = (const float*)d_in[2];
    float* O = (float*)d_out;
    if (ws_size >= WS_NEED) {
        fattn_kernel<1><<<dim3(1024), dim3(256), 0, stream>>>(Q, K, V, O, (char*)d_ws);
        merge_kernel<<<dim3(256), dim3(256), 0, stream>>>(O, (const char*)d_ws);
    } else {
        fattn_kernel<0><<<dim3(256), dim3(256), 0, stream>>>(Q, K, V, O, (char*)d_ws);
    }
}

// Round 24
// 115.590 us; speedup vs baseline: 3.0508x; 3.0508x over previous
//
#include <hip/hip_runtime.h>
#include <hip/hip_bf16.h>

typedef __attribute__((ext_vector_type(8))) short bf16x8;
typedef __attribute__((ext_vector_type(4))) float f32x4;
typedef __attribute__((ext_vector_type(16))) float f32x16;

#define DHEAD 64
#define L_SEQ 2048
#define QSCALE (0.125f * 1.44269504088896340736f)

// ws: [4KB, +2MB) ml float2[(bh*8+T)*4+s][256]
//     [4KB+2MB, +22MB) partial O bf16, compact slots [32*22][256][64]
//     slot(bh,T,s>=1) = bh*22 + (T==0 ? 0 : 1+(T-1)*3+(s-1))
#define WS_ML_OFF   4096
#define WS_PART_OFF (4096 + 32 * 8 * 4 * 256 * 8)
#define WS_NEED     ((size_t)WS_PART_OFF + (size_t)32 * 22 * 256 * 64 * 2)

union U4S8 { uint4 u; bf16x8 s; };

__device__ __forceinline__ unsigned pk2(float a, float b) {
    unsigned r;
    asm("v_cvt_pk_bf16_f32 %0, %1, %2" : "=v"(r) : "v"(a), "v"(b));
    return r;
}
__device__ __forceinline__ float bfrt(float x) {
    return __uint_as_float(pk2(x, x) << 16);
}
__device__ __forceinline__ float bf2f(unsigned short u) {
    return __uint_as_float((unsigned)u << 16);
}
__device__ __forceinline__ float fexp2(float x) {
#if __has_builtin(__builtin_amdgcn_exp2f)
    return __builtin_amdgcn_exp2f(x);
#else
    return __expf(x * 0.69314718055994530942f);
#endif
}

#if __has_builtin(__builtin_amdgcn_permlane32_swap)
__device__ __forceinline__ float xhalf_max(float x) {
    const unsigned u = __float_as_uint(x);
    const auto r = __builtin_amdgcn_permlane32_swap(u, u, false, false);
    return fmaxf(__uint_as_float(r[0]), __uint_as_float(r[1]));
}
__device__ __forceinline__ float xhalf_sum(float x) {
    const unsigned u = __float_as_uint(x);
    const auto r = __builtin_amdgcn_permlane32_swap(u, u, false, false);
    return __uint_as_float(r[0]) + __uint_as_float(r[1]);
}
#else
__device__ __forceinline__ float xhalf_max(float x) { return fmaxf(x, __shfl_xor(x, 32)); }
__device__ __forceinline__ float xhalf_sum(float x) { return x + __shfl_xor(x, 32); }
#endif

#define MAX16(P) fmaxf(fmaxf(fmaxf(fmaxf(P[0],P[1]),fmaxf(P[2],P[3])),          \
                             fmaxf(fmaxf(P[4],P[5]),fmaxf(P[6],P[7]))),         \
                       fmaxf(fmaxf(fmaxf(P[8],P[9]),fmaxf(P[10],P[11])),        \
                             fmaxf(fmaxf(P[12],P[13]),fmaxf(P[14],P[15]))))
#define SUM16(P) ((((P[0]+P[1])+(P[2]+P[3]))+((P[4]+P[5])+(P[6]+P[7])))         \
                + (((P[8]+P[9])+(P[10]+P[11]))+((P[12]+P[13])+(P[14]+P[15]))))

// QBLK=256: wave owns 64 q-rows (2 MFMA groups) -> per staged 128-key tile
// 32 MFMA/wave with UNCHANGED staging bytes (r21: bytes/tile is the residual).
// r23 lesson: launch_bounds(256,2) split the unified file 128 arch + 128 acc
// -> arch spilled 900MB. NO min-waves bound here: compiler allocates ~200-230
// total, zero spill, ~2 blocks/CU (occupancy proven non-binding r8-r17).
__constant__ unsigned char JOBS32[32] = {
    (7<<2)|0, (7<<2)|1, (7<<2)|2, (7<<2)|3, (6<<2)|0, (6<<2)|1,            // d=4
    (6<<2)|2, (6<<2)|3, (5<<2)|0, (5<<2)|1, (5<<2)|2, (5<<2)|3,
    (4<<2)|0, (4<<2)|1,                                                    // d=3
    (4<<2)|2, (4<<2)|3, (3<<2)|0, (3<<2)|1, (3<<2)|2, (3<<2)|3,
    (2<<2)|0, (2<<2)|1,                                                    // d=2
    (2<<2)|2, (2<<2)|3, (1<<2)|0, (1<<2)|1, (1<<2)|2, (1<<2)|3,
    (0<<2)|0, (0<<2)|1,                                                    // d=1
    (0<<2)|2, (0<<2)|3,                                                    // d=0
};

// LDS map (proven r13-r22): K chunk kb*4+kc, slot l: K[kb*32+(l&31)][kc*16+8*(l>>5)+j]
//                           V chunk kv*2+dt, slot l: V[kv*16+8*(l>>5)+j][dt*32+(l&31)]
template<int MODE>   // 1 = split4 + merge; 0 = basic (no ws)
__global__ __launch_bounds__(256)
void fattn_kernel(const float* __restrict__ Qg, const float* __restrict__ Kg,
                  const float* __restrict__ Vg, float* __restrict__ Og,
                  char* __restrict__ wsBase) {
    __shared__ uint4 sK4[16][64];
    __shared__ uint4 sV4[16][65];

    const int tid  = threadIdx.x;
    const int lane = tid & 63;
    const int w    = tid >> 6;
    const int hi   = lane >> 5;
    const int c    = lane & 31;

    const int id  = blockIdx.x;
    const int bh  = (id & 7) + 8 * ((id >> 3) & 3);   // 4 bh per XCD

    int T, s, kt0, kstep, d;
    if (MODE == 1) {
        const unsigned jb = JOBS32[id >> 5];          // LPT rank
        T = jb >> 2; s = jb & 3;
        d = (s <= 2 * T + 1) ? (((2 * T + 1 - s) >> 2) + 1) : 0;
        if (d == 0) return;
        kt0 = s; kstep = 4;
    } else {
        const int u_ = id >> 5;                       // grid 256: u 0..7
        T = (u_ < 4) ? (7 - u_) : (u_ - 4);
        s = 0; kt0 = 0; kstep = 1; d = 2 * T + 2;
    }

    const size_t base = (size_t)bh * L_SEQ * DHEAD;
    const int q0w = T * 256 + w * 64;    // this wave's 64 q-rows (2 groups of 32)

    // ---- Q fragments for both groups (B-operand), scale folded ----
    bf16x8 qf[2][4];
    #pragma unroll
    for (int g = 0; g < 2; ++g) {
        const float* Qrow = Qg + base + (size_t)(q0w + 32 * g + c) * DHEAD;
        #pragma unroll
        for (int kc = 0; kc < 4; ++kc) {
            float4 aa = *(const float4*)(Qrow + kc * 16 + hi * 8);
            float4 bb = *(const float4*)(Qrow + kc * 16 + hi * 8 + 4);
            U4S8 t;
            t.u = make_uint4(pk2(aa.x * QSCALE, aa.y * QSCALE),
                             pk2(aa.z * QSCALE, aa.w * QSCALE),
                             pk2(bb.x * QSCALE, bb.y * QSCALE),
                             pk2(bb.z * QSCALE, bb.w * QSCALE));
            qf[g][kc] = t.s;
        }
    }

    // ---- staging (r22-proven mappings) ----
    const float* Kpb = Kg + base + (size_t)(32 * w + c) * DHEAD + 32 * hi;
    const int kg = tid >> 4, dq = tid & 15;
    const float* VpB = Vg + base + (size_t)(kg * 8) * DHEAD + dq * 4;

    auto stage_K = [&](int kt) {
        float4 rk[8];
        const float* Kp = Kpb + (size_t)kt * 128 * DHEAD;
        #pragma unroll
        for (int t = 0; t < 8; ++t) rk[t] = *(const float4*)(Kp + 4 * t);
        #pragma unroll
        for (int q = 0; q < 2; ++q)
            #pragma unroll
            for (int hh = 0; hh < 2; ++hh) {
                const float4 r0 = rk[4 * q + 2 * hh], r1 = rk[4 * q + 2 * hh + 1];
                sK4[w * 4 + 2 * hi + q][hh * 32 + c] =
                    make_uint4(pk2(r0.x, r0.y), pk2(r0.z, r0.w),
                               pk2(r1.x, r1.y), pk2(r1.z, r1.w));
            }
    };
    auto stage_V = [&](int kt) {
        f32x4 rv4[8];
        const float* Vp = VpB + (size_t)kt * 128 * DHEAD;
        #pragma unroll
        for (int j = 0; j < 8; ++j) rv4[j] = *(const f32x4*)(Vp + j * DHEAD);
        #pragma unroll
        for (int dd = 0; dd < 4; ++dd) {
            const int dv = dq * 4 + dd;
            const int ch = (kg >> 1) * 2 + (dv >> 5);
            const int sl = ((kg & 1) << 5) | (dv & 31);
            sV4[ch][sl] = make_uint4(pk2(rv4[0][dd], rv4[1][dd]),
                                     pk2(rv4[2][dd], rv4[3][dd]),
                                     pk2(rv4[4][dd], rv4[5][dd]),
                                     pk2(rv4[6][dd], rv4[7][dd]));
        }
    };

    f32x16 o0[2], o1[2];
    #pragma unroll
    for (int g = 0; g < 2; ++g) {
        o0[g] = (f32x16){0,0,0,0,0,0,0,0,0,0,0,0,0,0,0,0};
        o1[g] = o0[g];
    }
    float m_r[2] = {-1e30f, -1e30f}, l_r[2] = {0.f, 0.f};

    stage_K(kt0);
    stage_V(kt0);
    __syncthreads();

    for (int j = 0; j < d; ++j) {
        const int  kt = kt0 + j * kstep;
        const bool pf = (j + 1 < d);

        #pragma unroll
        for (int sub = 0; sub < 2; ++sub) {
            #pragma unroll
            for (int g = 0; g < 2; ++g) {
                // causal: 32-key block 4kt+2sub+i live iff <= 8T+2w+g
                const int lim = 8 * T + 2 * w + g - (4 * kt + 2 * sub) + 1;
                const int nkb = lim < 0 ? 0 : (lim > 2 ? 2 : lim);
                if (nkb > 0) {
                    float p[2][16];

                    __builtin_amdgcn_s_setprio(1);
                    #pragma unroll
                    for (int i = 0; i < 2; ++i) {
                        if (i < nkb) {
                            f32x16 sa = {0,0,0,0,0,0,0,0,0,0,0,0,0,0,0,0};
                            #pragma unroll
                            for (int kc = 0; kc < 4; ++kc) {
                                U4S8 t; t.u = sK4[(2 * sub + i) * 4 + kc][lane];
                                sa = __builtin_amdgcn_mfma_f32_32x32x16_bf16(t.s, qf[g][kc], sa, 0, 0, 0);
                            }
                            #pragma unroll
                            for (int r = 0; r < 16; ++r) p[i][r] = sa[r];
                        }
                    }
                    __builtin_amdgcn_s_setprio(0);

                    // diagonal 32x32 mask (compile-time i, runtime condition)
                    #pragma unroll
                    for (int i = 0; i < 2; ++i) {
                        if (4 * kt + 2 * sub + i == 8 * T + 2 * w + g) {
                            #pragma unroll
                            for (int r = 0; r < 16; ++r) {
                                const int kk = (r & 3) + 8 * (r >> 2) + 4 * hi;
                                if (kk > c) p[i][r] = -1e30f;
                            }
                        }
                    }

                    float mx = MAX16(p[0]);
                    if (nkb > 1) mx = fmaxf(mx, MAX16(p[1]));
                    mx = xhalf_max(mx);

                    if (__any(mx > m_r[g] + 8.f)) {      // defer-max
                        const float mn    = fmaxf(m_r[g], mx);
                        const float alpha = fexp2(m_r[g] - mn);
                        m_r[g]  = mn;
                        l_r[g] *= alpha;
                        #pragma unroll
                        for (int r = 0; r < 16; ++r) {
                            const float ab = __shfl(alpha, (r & 3) + 8 * (r >> 2) + 4 * hi);
                            o0[g][r] *= ab; o1[g][r] *= ab;
                        }
                    }

                    #pragma unroll
                    for (int i = 0; i < 2; ++i) {
                        if (i < nkb) {
                            #pragma unroll
                            for (int r = 0; r < 16; ++r) p[i][r] = fexp2(p[i][r] - m_r[g]);
                        }
                    }
                    float rs = SUM16(p[0]);
                    if (nkb > 1) rs += SUM16(p[1]);
                    rs = xhalf_sum(rs);
                    l_r[g] += rs;

                    __builtin_amdgcn_s_setprio(1);
                    #pragma unroll
                    for (int kcl = 0; kcl < 4; ++kcl) {
                        if (kcl < 2 * nkb) {
                            const int i = kcl >> 1, bs = (kcl & 1) * 8;
                            unsigned a0 = pk2(p[i][bs + 0], p[i][bs + 1]);
                            unsigned a1 = pk2(p[i][bs + 2], p[i][bs + 3]);
                            unsigned b0 = pk2(p[i][bs + 4], p[i][bs + 5]);
                            unsigned b1 = pk2(p[i][bs + 6], p[i][bs + 7]);
                            asm("v_permlane32_swap_b32 %0, %1" : "+v"(a0), "+v"(b0));
                            asm("v_permlane32_swap_b32 %0, %1" : "+v"(a1), "+v"(b1));
                            U4S8 t;
                            t.u = make_uint4(a0, a1, b0, b1);
                            const int kv = 4 * sub + kcl;
                            U4S8 tv0; tv0.u = sV4[kv * 2][lane];
                            o0[g] = __builtin_amdgcn_mfma_f32_32x32x16_bf16(t.s, tv0.s, o0[g], 0, 0, 0);
                            U4S8 tv1; tv1.u = sV4[kv * 2 + 1][lane];
                            o1[g] = __builtin_amdgcn_mfma_f32_32x32x16_bf16(t.s, tv1.s, o1[g], 0, 0, 0);
                        }
                    }
                    __builtin_amdgcn_s_setprio(0);
                }
            }
        }

        if (pf) {
            __syncthreads();
            stage_K(kt + kstep);
            stage_V(kt + kstep);
            __syncthreads();
        }
    }

    float* Op = Og + base;

    if (MODE == 0) {
        #pragma unroll
        for (int g = 0; g < 2; ++g) {
            const float linv = 1.f / l_r[g];
            #pragma unroll
            for (int r = 0; r < 16; ++r) {
                const int   cr  = (r & 3) + 8 * (r >> 2) + 4 * hi;
                const float lb  = __shfl(linv, cr);
                const int   row = q0w + 32 * g + cr;
                Op[(size_t)row * DHEAD + c]      = o0[g][r] * lb;
                Op[(size_t)row * DHEAD + 32 + c] = o1[g][r] * lb;
            }
        }
        return;
    }

    // ---- publish partial, write-only; merge_kernel combines ----
    float2* ml = (float2*)(wsBase + WS_ML_OFF);
    const size_t mlb = (size_t)((bh * 8 + T) * 4 + s) * 256;
    #pragma unroll
    for (int g = 0; g < 2; ++g)
        if (hi == 0) ml[mlb + w * 64 + 32 * g + c] = make_float2(m_r[g], l_r[g]);
    if (s == 0) {           // seg0 partial (bf16-rounded, unnormalized) in d_out
        #pragma unroll
        for (int g = 0; g < 2; ++g)
            #pragma unroll
            for (int r = 0; r < 16; ++r) {
                const int cr  = (r & 3) + 8 * (r >> 2) + 4 * hi;
                const int row = q0w + 32 * g + cr;
                Op[(size_t)row * DHEAD + c]      = bfrt(o0[g][r]);
                Op[(size_t)row * DHEAD + 32 + c] = bfrt(o1[g][r]);
            }
    } else {                // seg>=1 partial as bf16 in compact ws slot
        const int ps = bh * 22 + (T == 0 ? 0 : 1 + (T - 1) * 3 + (s - 1));
        unsigned short* mp = (unsigned short*)(wsBase + WS_PART_OFF) + (size_t)ps * 256 * 64;
        #pragma unroll
        for (int g = 0; g < 2; ++g)
            #pragma unroll
            for (int r = 0; r < 16; ++r) {
                const int cr   = (r & 3) + 8 * (r >> 2) + 4 * hi;
                const int lrow = w * 64 + 32 * g + cr;
                mp[lrow * 64 + c]      = (unsigned short)pk2(o0[g][r], o0[g][r]);
                mp[lrow * 64 + 32 + c] = (unsigned short)pk2(o1[g][r], o1[g][r]);
            }
    }
}

// n-way merge: one block per (bh,T); n = min(4, 2T+2).
__global__ __launch_bounds__(256)
void merge_kernel(float* __restrict__ Og, const char* __restrict__ wsBase) {
    const int blk = blockIdx.x;           // 256 = 32 bh x 8 T
    const int bh = blk >> 3, T = blk & 7;
    const int n  = (T == 0) ? 2 : 4;
    const size_t f4 = (size_t)((bh * 8 + T) * 4);
    const int psb = bh * 22 + (T == 0 ? 0 : 1 + (T - 1) * 3);

    const float2* ml = (const float2*)(wsBase + WS_ML_OFF);
    const unsigned short* part = (const unsigned short*)(wsBase + WS_PART_OFF);
    const unsigned short* p1 = part + (size_t)(psb + 0) * 256 * 64;
    const unsigned short* p2 = part + (size_t)(psb + 1) * 256 * 64;
    const unsigned short* p3 = part + (size_t)(psb + 2) * 256 * 64;
    float* Op = Og + ((size_t)bh * L_SEQ + (size_t)T * 256) * DHEAD;

    __shared__ float sA0[256], sA1[256], sA2[256], sA3[256], sLi[256];
    const int t = threadIdx.x;
    {
        const float2 m0 = ml[(f4 + 0) * 256 + t];
        const float2 m1 = ml[(f4 + 1) * 256 + t];
        const float2 m2 = (n > 2) ? ml[(f4 + 2) * 256 + t] : make_float2(-1e30f, 0.f);
        const float2 m3 = (n > 3) ? ml[(f4 + 3) * 256 + t] : make_float2(-1e30f, 0.f);
        const float mM = fmaxf(fmaxf(m0.x, m1.x), fmaxf(m2.x, m3.x));
        const float a0 = fexp2(m0.x - mM), a1 = fexp2(m1.x - mM);
        const float a2 = fexp2(m2.x - mM), a3 = fexp2(m3.x - mM);
        sA0[t] = a0; sA1[t] = a1; sA2[t] = a2; sA3[t] = a3;
        sLi[t] = 1.f / (a0 * m0.y + a1 * m1.y + a2 * m2.y + a3 * m3.y);
    }
    __syncthreads();

    #pragma unroll
    for (int e = 0; e < 16; ++e) {
        const int idx4 = e * 256 + t;     // 4096 float4 groups (256 rows x 16)
        const int row  = idx4 >> 4;
        const int c4   = (idx4 & 15) * 4;
        const int off  = row * 64 + c4;
        const float a0 = sA0[row], li = sLi[row];
        float4 po = *(float4*)&Op[off];
        po.x *= a0; po.y *= a0; po.z *= a0; po.w *= a0;
        {
            const float a1 = sA1[row];
            const ushort4 u = *(const ushort4*)&p1[off];
            po.x += a1 * bf2f(u.x); po.y += a1 * bf2f(u.y);
            po.z += a1 * bf2f(u.z); po.w += a1 * bf2f(u.w);
        }
        if (n > 2) {
            const float a2 = sA2[row];
            const ushort4 u = *(const ushort4*)&p2[off];
            po.x += a2 * bf2f(u.x); po.y += a2 * bf2f(u.y);
            po.z += a2 * bf2f(u.z); po.w += a2 * bf2f(u.w);
        }
        if (n > 3) {
            const float a3 = sA3[row];
            const ushort4 u = *(const ushort4*)&p3[off];
            po.x += a3 * bf2f(u.x); po.y += a3 * bf2f(u.y);
            po.z += a3 * bf2f(u.z); po.w += a3 * bf2f(u.w);
        }
        po.x *= li; po.y *= li; po.z *= li; po.w *= li;
        *(float4*)&Op[off] = po;
    }
}

extern "C" void kernel_launch(void* const* d_in, const int* in_sizes, int n_in,
                              void* d_out, int out_size, void* d_ws, size_t ws_size,
                              hipStream_t stream) {
    const float* Q = (const float*)d_in[0];
    const float* K = (const float*)d_in[1];
    const float* V = (const float*)d_in[2];
    float* O = (float*)d_out;
    if (ws_size >= WS_NEED) {
        fattn_kernel<1><<<dim3(1024), dim3(256), 0, stream>>>(Q, K, V, O, (char*)d_ws);
        merge_kernel<<<dim3(256), dim3(256), 0, stream>>>(O, (const char*)d_ws);
    } else {
        fattn_kernel<0><<<dim3(256), dim3(256), 0, stream>>>(Q, K, V, O, (char*)d_ws);
    }
}

// Round 25
// 51.729 us; speedup vs baseline: 6.8171x; 2.2345x over previous
//
#include <hip/hip_runtime.h>
#include <hip/hip_bf16.h>

typedef __attribute__((ext_vector_type(8))) short bf16x8;
typedef __attribute__((ext_vector_type(16))) float f32x16;

#define DHEAD 64
#define L_SEQ 2048
// softmax scale 1/8 folded with log2(e): exp(x/8) == exp2(x*QSCALE)
#define QSCALE (0.125f * 1.44269504088896340736f)

// ws layout: [4KB, 4KB+1MB) ml float2[512][2][128];
// [4KB+1MB, +8MB) h=1 bf16 partial O [512][128][64]
#define WS_ML_OFF   4096
#define WS_PART_OFF (4096 + 512 * 2 * 128 * 8)
#define WS_NEED     ((size_t)WS_PART_OFF + (size_t)512 * 128 * 64 * 2)

union U4S8 { uint4 u; bf16x8 s; };

// Single-instruction f32x2 -> bf16x2 pack (RNE); no builtin on gfx950.
__device__ __forceinline__ unsigned pk2(float a, float b) {
    unsigned r;
    asm("v_cvt_pk_bf16_f32 %0, %1, %2" : "=v"(r) : "v"(a), "v"(b));
    return r;
}
__device__ __forceinline__ float bfrt(float x) {
    return __uint_as_float(pk2(x, x) << 16);
}
__device__ __forceinline__ float bf2f(unsigned short u) {
    return __uint_as_float((unsigned)u << 16);
}

__device__ __forceinline__ float fexp2(float x) {
#if __has_builtin(__builtin_amdgcn_exp2f)
    return __builtin_amdgcn_exp2f(x);
#else
    return __expf(x * 0.69314718055994530942f);
#endif
}

// Cross-half (lane ^ 32) reductions via the permlane32_swap BUILTIN (compiler
// owns regalloc + hazard nops; r18/r19 showed hand-asm versions break on
// operand coalescing / VALU->permlane wait states).
#if __has_builtin(__builtin_amdgcn_permlane32_swap)
__device__ __forceinline__ float xhalf_max(float x) {
    const unsigned u = __float_as_uint(x);
    const auto r = __builtin_amdgcn_permlane32_swap(u, u, false, false);
    return fmaxf(__uint_as_float(r[0]), __uint_as_float(r[1]));
}
__device__ __forceinline__ float xhalf_sum(float x) {
    const unsigned u = __float_as_uint(x);
    const auto r = __builtin_amdgcn_permlane32_swap(u, u, false, false);
    return __uint_as_float(r[0]) + __uint_as_float(r[1]);
}
#else
__device__ __forceinline__ float xhalf_max(float x) { return fmaxf(x, __shfl_xor(x, 32)); }
__device__ __forceinline__ float xhalf_sum(float x) { return x + __shfl_xor(x, 32); }
#endif

// Depth-4 trees, constant-index only (rule #20: runtime-indexing p -> scratch).
#define MAX16(P) fmaxf(fmaxf(fmaxf(fmaxf(P[0],P[1]),fmaxf(P[2],P[3])),          \
                             fmaxf(fmaxf(P[4],P[5]),fmaxf(P[6],P[7]))),         \
                       fmaxf(fmaxf(fmaxf(P[8],P[9]),fmaxf(P[10],P[11])),        \
                             fmaxf(fmaxf(P[12],P[13]),fmaxf(P[14],P[15]))))
#define SUM16(P) ((((P[0]+P[1])+(P[2]+P[3]))+((P[4]+P[5])+(P[6]+P[7])))         \
                + (((P[8]+P[9])+(P[10]+P[11]))+((P[12]+P[13])+(P[14]+P[15]))))

// FINAL (best measured, r20 = 51.8us, absmax 0.015625, VGPR 76, 0 conflicts):
// p[2][16] register diet, single-buffered 32KB LDS, stage load->write
// immediately (reg prefetch spills: r15), 1024 jobs = 32bh x 16T x 2 kv
// parities LPT, separate merge kernel (no in-launch cross-block sync: r10).
// LDS chunk map (all ds ops chunk_base + lane*16, conflict-free):
//  K chunk kb*4+kc, slot l: K[kb*32+(l&31)][kc*16+8*(l>>5)+j]
//  V chunk kv*2+dt, slot l: V[kv*16+8*(l>>5)+j][dt*32+(l&31)]  (kv=0..7)

template<int SPLIT>
__global__ __launch_bounds__(256, 3)
void fattn_kernel(const float* __restrict__ Qg, const float* __restrict__ Kg,
                  const float* __restrict__ Vg, float* __restrict__ Og,
                  char* __restrict__ wsBase) {
    __shared__ uint4 sK4[16][64];
    __shared__ uint4 sV4[16][64];

    const int tid  = threadIdx.x;
    const int lane = tid & 63;
    const int w    = tid >> 6;     // wave -> rows 32w..32w+31 of this block's q-tile
    const int hi   = lane >> 5;
    const int c    = lane & 31;

    const int id  = blockIdx.x;
    const int bh  = (id & 7) + 8 * ((id >> 3) & 3);   // 4 bh per XCD

    int T, h, kt0, kstep, d;
    if (SPLIT) {
        const int k31 = 31 - (id >> 5);   // rank 0 = heaviest (LPT)
        T = k31 >> 1;
        h = 1 - (k31 & 1);
        d = (T + 2 - h) >> 1;             // # kv tiles of parity h for q-tile T
        if (d == 0) return;               // T=0, h=1: empty job
        kt0 = h; kstep = 2;
    } else {                              // fallback schedule (no ws needed)
        const int u_ = id >> 5;
        T = (u_ < 8) ? (15 - u_) : (u_ - 8);
        h = 0; d = T + 1; kt0 = 0; kstep = 1;
    }

    const size_t base = (size_t)bh * L_SEQ * DHEAD;
    const int q0w = T * 128 + w * 32;     // this wave's q rows

    // ---- Q fragments (B-operand), scale folded ----
    bf16x8 qf[4];
    {
        const float* Qrow = Qg + base + (size_t)(q0w + c) * DHEAD;
        #pragma unroll
        for (int kc = 0; kc < 4; ++kc) {
            float4 aa = *(const float4*)(Qrow + kc * 16 + hi * 8);
            float4 bb = *(const float4*)(Qrow + kc * 16 + hi * 8 + 4);
            U4S8 t;
            t.u = make_uint4(pk2(aa.x * QSCALE, aa.y * QSCALE),
                             pk2(aa.z * QSCALE, aa.w * QSCALE),
                             pk2(bb.x * QSCALE, bb.y * QSCALE),
                             pk2(bb.z * QSCALE, bb.w * QSCALE));
            qf[kc] = t.s;
        }
    }

    // ---- staging bases: thread (w,hi,c) ----
    const float* Kpb = Kg + base + (size_t)(32 * w + c) * DHEAD + 32 * hi;
    const float* Vpb = Vg + base + (size_t)(32 * w + 16 * hi) * DHEAD + c;

    auto stage_K = [&](int kt) {          // 32 floats live peak
        float4 rk[8];
        const float* Kp = Kpb + (size_t)kt * 128 * DHEAD;
        #pragma unroll
        for (int t = 0; t < 8; ++t) rk[t] = *(const float4*)(Kp + 4 * t);
        #pragma unroll
        for (int q = 0; q < 2; ++q)
            #pragma unroll
            for (int hh = 0; hh < 2; ++hh) {
                const float4 r0 = rk[4 * q + 2 * hh], r1 = rk[4 * q + 2 * hh + 1];
                sK4[w * 4 + 2 * hi + q][hh * 32 + c] =
                    make_uint4(pk2(r0.x, r0.y), pk2(r0.z, r0.w),
                               pk2(r1.x, r1.y), pk2(r1.z, r1.w));
            }
    };
    auto stage_V = [&](int kt) {          // 32 floats live peak
        float rv[32];
        const float* Vp = Vpb + (size_t)kt * 128 * DHEAD;
        #pragma unroll
        for (int j = 0; j < 16; ++j) {
            rv[j]      = Vp[j * DHEAD];
            rv[16 + j] = Vp[j * DHEAD + 32];
        }
        #pragma unroll
        for (int dt = 0; dt < 2; ++dt)
            #pragma unroll
            for (int hh = 0; hh < 2; ++hh) {
                const int b = 16 * dt + 8 * hh;
                sV4[(2 * w + hi) * 2 + dt][hh * 32 + c] =
                    make_uint4(pk2(rv[b + 0], rv[b + 1]), pk2(rv[b + 2], rv[b + 3]),
                               pk2(rv[b + 4], rv[b + 5]), pk2(rv[b + 6], rv[b + 7]));
            }
    };

    f32x16 o0 = {0,0,0,0,0,0,0,0,0,0,0,0,0,0,0,0};
    f32x16 o1 = o0;
    float m_r = -1e30f, l_r = 0.f;

    stage_K(kt0);
    stage_V(kt0);
    __syncthreads();

    for (int j = 0; j < d; ++j) {
        const int  kt   = kt0 + j * kstep;
        const bool pf   = (j + 1 < d);
        const bool diag = (kt == T);

        // two 64-key sub-passes over the staged 128-key tile (p[2][16] diet)
        #pragma unroll
        for (int sub = 0; sub < 2; ++sub) {
            const int lim = diag ? (w + 1 - 2 * sub) : 2;   // live 32-key blocks
            const int nkb = lim < 0 ? 0 : (lim > 2 ? 2 : lim);
            if (nkb > 0) {
                float p[2][16];

                // ---- S^T = K * Q^T (kb_global = 2*sub + i) ----
                __builtin_amdgcn_s_setprio(1);
                #pragma unroll
                for (int i = 0; i < 2; ++i) {
                    if (i < nkb) {
                        f32x16 s = {0,0,0,0,0,0,0,0,0,0,0,0,0,0,0,0};
                        #pragma unroll
                        for (int kc = 0; kc < 4; ++kc) {
                            U4S8 t; t.u = sK4[(2 * sub + i) * 4 + kc][lane];
                            s = __builtin_amdgcn_mfma_f32_32x32x16_bf16(t.s, qf[kc], s, 0, 0, 0);
                        }
                        #pragma unroll
                        for (int r = 0; r < 16; ++r) p[i][r] = s[r];
                    }
                }
                __builtin_amdgcn_s_setprio(0);

                // diagonal mask: compile-time index, runtime CONDITION only
                #pragma unroll
                for (int i = 0; i < 2; ++i) {
                    if (diag && (2 * sub + i) == w) {
                        #pragma unroll
                        for (int r = 0; r < 16; ++r) {
                            const int kk = (r & 3) + 8 * (r >> 2) + 4 * hi;
                            if (kk > c) p[i][r] = -1e30f;
                        }
                    }
                }

                // ---- online softmax over nkb*32 keys ----
                float mx = MAX16(p[0]);
                if (nkb > 1) mx = fmaxf(mx, MAX16(p[1]));
                mx = xhalf_max(mx);

                if (__any(mx > m_r + 8.f)) {      // defer-max (T13)
                    const float mn    = fmaxf(m_r, mx);
                    const float alpha = fexp2(m_r - mn);
                    m_r  = mn;
                    l_r *= alpha;
                    #pragma unroll
                    for (int r = 0; r < 16; ++r) {
                        const float ab = __shfl(alpha, (r & 3) + 8 * (r >> 2) + 4 * hi);
                        o0[r] *= ab; o1[r] *= ab;
                    }
                }

                #pragma unroll
                for (int i = 0; i < 2; ++i) {
                    if (i < nkb) {
                        #pragma unroll
                        for (int r = 0; r < 16; ++r) p[i][r] = fexp2(p[i][r] - m_r);
                    }
                }
                float rs = SUM16(p[0]);
                if (nkb > 1) rs += SUM16(p[1]);
                rs = xhalf_sum(rs);
                l_r += rs;

                // ---- P -> A-frags (permlane32_swap) + O += P V ----
                __builtin_amdgcn_s_setprio(1);
                #pragma unroll
                for (int kcl = 0; kcl < 4; ++kcl) {
                    if (kcl < 2 * nkb) {
                        const int i = kcl >> 1, bs = (kcl & 1) * 8;
                        unsigned a0 = pk2(p[i][bs + 0], p[i][bs + 1]);
                        unsigned a1 = pk2(p[i][bs + 2], p[i][bs + 3]);
                        unsigned b0 = pk2(p[i][bs + 4], p[i][bs + 5]);
                        unsigned b1 = pk2(p[i][bs + 6], p[i][bs + 7]);
                        asm("v_permlane32_swap_b32 %0, %1" : "+v"(a0), "+v"(b0));
                        asm("v_permlane32_swap_b32 %0, %1" : "+v"(a1), "+v"(b1));
                        U4S8 t;
                        t.u = make_uint4(a0, a1, b0, b1);
                        const int kv = 4 * sub + kcl;        // 16-key V slice
                        U4S8 tv0; tv0.u = sV4[kv * 2][lane];
                        o0 = __builtin_amdgcn_mfma_f32_32x32x16_bf16(t.s, tv0.s, o0, 0, 0, 0);
                        U4S8 tv1; tv1.u = sV4[kv * 2 + 1][lane];
                        o1 = __builtin_amdgcn_mfma_f32_32x32x16_bf16(t.s, tv1.s, o1, 0, 0, 0);
                    }
                }
                __builtin_amdgcn_s_setprio(0);
            }
        }

        if (pf) {                           // single buffer: drain reads, restage
            __syncthreads();
            stage_K(kt + kstep);
            stage_V(kt + kstep);
            __syncthreads();
        }
    }

    float* Op = Og + base;

    if (!SPLIT || T == 0) {
        // ---- single contributor: normalize, store final ----
        const float linv = 1.f / l_r;
        #pragma unroll
        for (int r = 0; r < 16; ++r) {
            const int   cr  = (r & 3) + 8 * (r >> 2) + 4 * hi;
            const float lb  = __shfl(linv, cr);
            const int   row = q0w + cr;
            Op[(size_t)row * DHEAD + c]      = o0[r] * lb;
            Op[(size_t)row * DHEAD + 32 + c] = o1[r] * lb;
        }
        return;
    }

    // ---- publish partial, write-only; merge_kernel combines ----
    const int f = bh * 16 + T;
    float2* ml = (float2*)(wsBase + WS_ML_OFF);
    if (hi == 0) ml[((size_t)f * 2 + h) * 128 + w * 32 + c] = make_float2(m_r, l_r);
    if (h == 0) {           // h=0 partial lives (bf16-rounded, unnormalized) in d_out
        #pragma unroll
        for (int r = 0; r < 16; ++r) {
            const int cr  = (r & 3) + 8 * (r >> 2) + 4 * hi;
            const int row = q0w + cr;
            Op[(size_t)row * DHEAD + c]      = bfrt(o0[r]);
            Op[(size_t)row * DHEAD + 32 + c] = bfrt(o1[r]);
        }
    } else {                // h=1 partial as bf16 in ws
        unsigned short* mp = (unsigned short*)(wsBase + WS_PART_OFF) + (size_t)f * 128 * 64;
        #pragma unroll
        for (int r = 0; r < 16; ++r) {
            const int cr   = (r & 3) + 8 * (r >> 2) + 4 * hi;
            const int lrow = w * 32 + cr;
            mp[lrow * 64 + c]      = (unsigned short)pk2(o0[r], o0[r]);
            mp[lrow * 64 + 32 + c] = (unsigned short)pk2(o1[r], o1[r]);
        }
    }
}

// Streaming merge: one block per (bh,T), exact online-softmax combine.
__global__ __launch_bounds__(256)
void merge_kernel(float* __restrict__ Og, const char* __restrict__ wsBase) {
    const int blk = blockIdx.x;           // 512 = 32 bh x 16 T
    const int bh = blk >> 4, T = blk & 15;
    if (T == 0) return;                   // written final by fattn_kernel
    const int f = bh * 16 + T;

    const float2* ml = (const float2*)(wsBase + WS_ML_OFF);
    const unsigned short* part =
        (const unsigned short*)(wsBase + WS_PART_OFF) + (size_t)f * 128 * 64;
    float* Op = Og + ((size_t)bh * L_SEQ + (size_t)T * 128) * DHEAD;

    __shared__ float sA0[128], sA1[128], sLi[128];
    const int t = threadIdx.x;
    if (t < 128) {
        const float2 m0 = ml[((size_t)f * 2 + 0) * 128 + t];
        const float2 m1 = ml[((size_t)f * 2 + 1) * 128 + t];
        const float mM = fmaxf(m0.x, m1.x);
        const float a0 = fexp2(m0.x - mM);
        const float a1 = fexp2(m1.x - mM);
        sA0[t] = a0; sA1[t] = a1;
        sLi[t] = 1.f / (a0 * m0.y + a1 * m1.y);
    }
    __syncthreads();

    #pragma unroll
    for (int e = 0; e < 8; ++e) {
        const int idx4 = e * 256 + t;     // 2048 float4 groups (128 rows x 16)
        const int row  = idx4 >> 4;
        const int c4   = (idx4 & 15) * 4;
        const float a0 = sA0[row], a1 = sA1[row], li = sLi[row];
        float4 po = *(float4*)&Op[row * 64 + c4];
        const ushort4 u = *(const ushort4*)&part[row * 64 + c4];
        po.x = (a0 * po.x + a1 * bf2f(u.x)) * li;
        po.y = (a0 * po.y + a1 * bf2f(u.y)) * li;
        po.z = (a0 * po.z + a1 * bf2f(u.z)) * li;
        po.w = (a0 * po.w + a1 * bf2f(u.w)) * li;
        *(float4*)&Op[row * 64 + c4] = po;
    }
}

extern "C" void kernel_launch(void* const* d_in, const int* in_sizes, int n_in,
                              void* d_out, int out_size, void* d_ws, size_t ws_size,
                              hipStream_t stream) {
    const float* Q = (const float*)d_in[0];
    const float* K = (const float*)d_in[1];
    const float* V = (const float*)d_in[2];
    float* O = (float*)d_out;
    if (ws_size >= WS_NEED) {
        fattn_kernel<1><<<dim3(1024), dim3(256), 0, stream>>>(Q, K, V, O, (char*)d_ws);
        merge_kernel<<<dim3(512), dim3(256), 0, stream>>>(O, (const char*)d_ws);
    } else {                                     // ws too small: fallback schedule
        fattn_kernel<0><<<dim3(512), dim3(256), 0, stream>>>(Q, K, V, O, (char*)d_ws);
    }
}